// Round 10
// baseline (135.313 us; speedup 1.0000x reference)
//
#include <hip/hip_runtime.h>

// GCN block: delta = segment_sum( (x @ W^T)[source] * ew, target )
//          = segment_sum( x[source] * ew, target ) @ W^T   (linearity)
//
// R10: R9 pipeline with the epilogue rebuilt per the R9 counters (284K LDS
// bank conflicts; 64 ds_read_b64/node made the epilogue co-dominant):
//  - W lives in per-lane VGPRs (loaded AFTER the gather loop), epilogue
//    reads only broadcast ds_read_b128 of accRow -> 16 LDS instr/node, 0 conflicts.
//  - wave-0 shfl scan replaces the 18-barrier block scan per chunk.
//  - convert(x->bf16) fused with bucket hist (one less dispatch).

#define D     64     // D_IN == D_OUT == 64
#define BKT   64     // nodes per bucket
#define BSH   6      // log2(BKT)
#define NBMAX 2048   // max buckets (scan kernel: 2/thread * 1024)
#define CAP   1024   // edges per in-LDS sort chunk (avg bucket ~640)

// ---------------- fallback: atomic edge scatter (R1) ----------------
__global__ __launch_bounds__(256) void gcn_scatter_kernel(
    const float* __restrict__ x, const float* __restrict__ ew,
    const int* __restrict__ src, const int* __restrict__ tgt,
    float* __restrict__ s, int n_edges)
{
    int lane = threadIdx.x & 63;
    int e = blockIdx.x * 4 + (threadIdx.x >> 6);
    if (e >= n_edges) return;
    int sn = src[e];
    int tn = tgt[e];
    float w = ew[e];
    float v = x[(size_t)sn * D + lane] * w;
    atomicAdd(&s[(size_t)tn * D + lane], v);
}

// ---------------- fallback: out = s @ W^T (R1) ----------------
__global__ __launch_bounds__(256) void gcn_gemm_kernel(
    const float* __restrict__ s, const float* __restrict__ W,
    float* __restrict__ out, int n_nodes)
{
    __shared__ float4 xs[64 * 17];
    const int tid  = threadIdx.x;
    const int lane = tid & 63;
    const int wid  = __builtin_amdgcn_readfirstlane(tid >> 6);
    const int row0 = blockIdx.x * 64;

    const float4* s4 = reinterpret_cast<const float4*>(s);
#pragma unroll
    for (int k = 0; k < 4; ++k) {
        int f  = tid + k * 256;
        int r  = f >> 4;
        int c4 = f & 15;
        float4 v = make_float4(0.f, 0.f, 0.f, 0.f);
        if (row0 + r < n_nodes)
            v = s4[(size_t)(row0 + r) * 16 + c4];
        xs[r * 17 + c4] = v;
    }
    __syncthreads();

    float acc[16];
#pragma unroll
    for (int j = 0; j < 16; ++j) acc[j] = 0.f;

    const int o0 = wid * 16;
    const float4* W4 = reinterpret_cast<const float4*>(W);
#pragma unroll
    for (int d4 = 0; d4 < 16; ++d4) {
        float4 xv = xs[lane * 17 + d4];
#pragma unroll
        for (int j = 0; j < 16; ++j) {
            float4 wv = W4[(size_t)(o0 + j) * 16 + d4];
            acc[j] += xv.x * wv.x + xv.y * wv.y + xv.z * wv.z + xv.w * wv.w;
        }
    }

    const int row = row0 + lane;
    if (row < n_nodes) {
        float4* out4 = reinterpret_cast<float4*>(out);
#pragma unroll
        for (int j4 = 0; j4 < 4; ++j4) {
            float4 v = make_float4(acc[j4 * 4 + 0], acc[j4 * 4 + 1],
                                   acc[j4 * 4 + 2], acc[j4 * 4 + 3]);
            out4[(size_t)row * 16 + wid * 4 + j4] = v;
        }
    }
}

// ---------------- A: fused x->bf16 convert + bucket histogram ----------
__device__ __forceinline__ unsigned f2bf(float f) {
    unsigned u = __float_as_uint(f);
    return (u + 0x7FFFu + ((u >> 16) & 1u)) >> 16;   // RNE; inputs finite
}

__global__ __launch_bounds__(256) void convert_hist_kernel(
    const float* __restrict__ x, uint2* __restrict__ xb, int n4,
    const int* __restrict__ tgt, int* __restrict__ bcnt,
    int n_edges, int nb, int epb)
{
    __shared__ int h[NBMAX];
    const int tid = threadIdx.x;
    for (int i = tid; i < nb; i += 256) h[i] = 0;

    // convert (grid-stride, independent of h)
    const float4* x4 = reinterpret_cast<const float4*>(x);
    for (int i = blockIdx.x * 256 + tid; i < n4; i += gridDim.x * 256) {
        float4 v = x4[i];
        uint2 o;
        o.x = f2bf(v.x) | (f2bf(v.y) << 16);
        o.y = f2bf(v.z) | (f2bf(v.w) << 16);
        xb[i] = o;
    }
    __syncthreads();

    const int e0 = blockIdx.x * epb;
    const int e1 = min(e0 + epb, n_edges);
    for (int e = e0 + tid; e < e1; e += 256)
        atomicAdd(&h[tgt[e] >> BSH], 1);
    __syncthreads();
    for (int b = tid; b < nb; b += 256) {
        int c = h[b];
        if (c) atomicAdd(&bcnt[b], c);
    }
}

// ---------------- B: exclusive scan of bucket counts (nb <= 2048) ----------
__global__ __launch_bounds__(1024) void bucket_scan_kernel(
    const int* __restrict__ bcnt, int* __restrict__ bstarts,
    int* __restrict__ bcur, int nb)
{
    __shared__ int lds[1024];
    const int tid = threadIdx.x;
    const int i0 = 2 * tid, i1 = 2 * tid + 1;
    int v0 = (i0 < nb) ? bcnt[i0] : 0;
    int v1 = (i1 < nb) ? bcnt[i1] : 0;
    int tsum = v0 + v1;
    lds[tid] = tsum;
    __syncthreads();
    for (int off = 1; off < 1024; off <<= 1) {
        int a = (tid >= off) ? lds[tid - off] : 0;
        __syncthreads();
        lds[tid] += a;
        __syncthreads();
    }
    int pre = lds[tid] - tsum;     // exclusive
    if (i0 < nb) { bstarts[i0] = pre;      bcur[i0] = pre; }
    if (i1 < nb) { bstarts[i1] = pre + v0; bcur[i1] = pre + v0; }
}

// ---------------- C: scatter edges into bucket-contiguous runs ----------
__global__ __launch_bounds__(256) void bucket_scatter_kernel(
    const int* __restrict__ src, const int* __restrict__ tgt,
    const float* __restrict__ ew, int* __restrict__ bcur,
    int2* __restrict__ pairs, int n_edges, int nb, int epb)
{
    __shared__ int h[NBMAX];        // counts, then rank counters
    __shared__ int base[NBMAX];
    const int tid = threadIdx.x;
    for (int i = tid; i < nb; i += 256) h[i] = 0;
    __syncthreads();
    const int e0 = blockIdx.x * epb;
    const int e1 = min(e0 + epb, n_edges);

    for (int e = e0 + tid; e < e1; e += 256)
        atomicAdd(&h[tgt[e] >> BSH], 1);
    __syncthreads();

    for (int b = tid; b < nb; b += 256) {
        int c = h[b];
        base[b] = c ? atomicAdd(&bcur[b], c) : 0;
        h[b] = 0;                   // reuse as rank counter
    }
    __syncthreads();

    for (int e = e0 + tid; e < e1; e += 256) {
        int t = tgt[e];
        int b = t >> BSH;
        int r = atomicAdd(&h[b], 1);
        pairs[base[b] + r] =
            make_int2(((t & (BKT - 1)) << 24) | src[e], __float_as_int(ew[e]));
    }
}

// ---------------- D: per-bucket LDS sort + bf16 quad-gather + reg-W GEMM ---
// One block per bucket (64 nodes), 8 waves. Quarter q = lane>>4 handles
// edge e+q; dwordx2 fetches 4 bf16 feats (4 edge rows per instruction).
// Epilogue: W row in per-lane VGPRs (loaded after gather loop), accRow via
// broadcast ds_read_b128 (conflict-free) -> 16 LDS instr + 64 FMA per node.
__global__ __launch_bounds__(512, 4) void bucket_sort_reduce_gemm_kernel(
    const uint2* __restrict__ xb, const float* __restrict__ W,
    const int* __restrict__ bstarts, const int2* __restrict__ pairs,
    float* __restrict__ out, int n_nodes, int n_edges, int nb)
{
    __shared__ int2  ep[CAP];                     // 8 KB, node-sorted chunk
    __shared__ int   segIncl[BKT];                // inclusive per-node counts
    __shared__ int   rankc[BKT];                  // scatter cursors
    __shared__ __align__(16) float accRow[8][64]; // per-wave row buffer

    const int tid  = threadIdx.x;
    const int lane = tid & 63;
    const int wv   = tid >> 6;          // 0..7
    const int q4   = lane >> 4;         // quarter 0..3
    const int m    = lane & 15;         // feature-quad index

    const int b   = blockIdx.x;
    const int beg = bstarts[b];
    const int end = (b + 1 < nb) ? bstarts[b + 1] : n_edges;

    float4 acc[8];
#pragma unroll
    for (int s = 0; s < 8; ++s) acc[s] = make_float4(0.f, 0.f, 0.f, 0.f);

    for (int cbeg = beg; cbeg < end; cbeg += CAP) {
        const int ccnt = min(CAP, end - cbeg);

        // -- zero hist --
        if (tid < BKT) segIncl[tid] = 0;
        __syncthreads();

        // -- pass 1: histogram tloc --
        for (int i = tid; i < ccnt; i += 512) {
            unsigned px = (unsigned)pairs[cbeg + i].x;
            atomicAdd(&segIncl[px >> 24], 1);
        }
        __syncthreads();

        // -- 64-bin scan by wave 0 (shfl, no block barriers inside) --
        if (wv == 0) {
            int c0 = segIncl[lane];
            int v = c0;
#pragma unroll
            for (int off = 1; off < 64; off <<= 1) {
                int n = __shfl_up(v, off);
                if (lane >= off) v += n;
            }
            segIncl[lane] = v;          // inclusive
            rankc[lane]   = v - c0;     // exclusive start
        }
        __syncthreads();

        // -- pass 2: scatter into node-sorted LDS --
        for (int i = tid; i < ccnt; i += 512) {
            int2 p = pairs[cbeg + i];
            int tl = ((unsigned)p.x) >> 24;
            int pos = atomicAdd(&rankc[tl], 1);
            ep[pos] = p;
        }
        __syncthreads();

        // -- bf16 quad-gather segreduce: wave wv owns tl = s*8+wv --
#pragma unroll
        for (int s = 0; s < 8; ++s) {
            const int tl = s * 8 + wv;
            const int s0 = __builtin_amdgcn_readfirstlane(tl ? segIncl[tl - 1] : 0);
            const int s1 = __builtin_amdgcn_readfirstlane(segIncl[tl]);
            float4 a = acc[s];
            for (int e = s0; e < s1; e += 8) {
                const int ea = e + q4;
                const int eb = e + 4 + q4;
                int2 p0 = ep[min(ea, s1 - 1)];
                int2 p1 = ep[min(eb, s1 - 1)];
                float w0 = (ea < s1) ? __int_as_float(p0.y) : 0.f;
                float w1 = (eb < s1) ? __int_as_float(p1.y) : 0.f;
                uint2 r0 = xb[(size_t)(p0.x & 0xFFFFFF) * 16 + m];   // 4 bf16
                uint2 r1 = xb[(size_t)(p1.x & 0xFFFFFF) * 16 + m];
                a.x += w0 * __uint_as_float(r0.x << 16);
                a.y += w0 * __uint_as_float(r0.x & 0xFFFF0000u);
                a.z += w0 * __uint_as_float(r0.y << 16);
                a.w += w0 * __uint_as_float(r0.y & 0xFFFF0000u);
                a.x += w1 * __uint_as_float(r1.x << 16);
                a.y += w1 * __uint_as_float(r1.x & 0xFFFF0000u);
                a.z += w1 * __uint_as_float(r1.y << 16);
                a.w += w1 * __uint_as_float(r1.y & 0xFFFF0000u);
            }
            acc[s] = a;
        }
        __syncthreads();   // protect ep/segIncl before next chunk
    }

    // -- load W row into VGPRs (only live during epilogue) --
    float4 wr4[16];
    {
        const float4* Wrow = reinterpret_cast<const float4*>(W + lane * D);
#pragma unroll
        for (int i = 0; i < 16; ++i) wr4[i] = Wrow[i];
    }

    // -- epilogue: merge quarters, out[node][o] = sum_d row[d]*W[o][d] --
    const int node0 = b * BKT;
#pragma unroll
    for (int s = 0; s < 8; ++s) {
        const int node = node0 + s * 8 + wv;
        if (node < n_nodes) {
            float4 a = acc[s];
            a.x += __shfl_xor(a.x, 16); a.y += __shfl_xor(a.y, 16);
            a.z += __shfl_xor(a.z, 16); a.w += __shfl_xor(a.w, 16);
            a.x += __shfl_xor(a.x, 32); a.y += __shfl_xor(a.y, 32);
            a.z += __shfl_xor(a.z, 32); a.w += __shfl_xor(a.w, 32);
            if (lane < 16)
                *reinterpret_cast<float4*>(&accRow[wv][m * 4]) = a;
            asm volatile("s_waitcnt lgkmcnt(0)" ::: "memory");

            float o = 0.f;
            const float4* a4p = reinterpret_cast<const float4*>(&accRow[wv][0]);
#pragma unroll
            for (int d4 = 0; d4 < 16; ++d4) {
                float4 aq = a4p[d4];    // same-address broadcast, conflict-free
                float4 wq = wr4[d4];    // register operand
                o += aq.x * wq.x + aq.y * wq.y + aq.z * wq.z + aq.w * wq.w;
            }
            out[(size_t)node * D + lane] = o;
            asm volatile("s_waitcnt lgkmcnt(0)" ::: "memory"); // drain before overwrite
        }
    }
}

extern "C" void kernel_launch(void* const* d_in, const int* in_sizes, int n_in,
                              void* d_out, int out_size, void* d_ws, size_t ws_size,
                              hipStream_t stream)
{
    const float* x   = (const float*)d_in[0];
    const float* W   = (const float*)d_in[1];
    const float* ew  = (const float*)d_in[2];
    const int*   src = (const int*)d_in[3];
    const int*   tgt = (const int*)d_in[4];

    const int n_nodes = in_sizes[0] / D;
    const int n_edges = in_sizes[2];
    const int nb = (n_nodes + BKT - 1) / BKT;

    // ---- workspace layout ----
    int*  bcnt    = (int*)d_ws;                   // NBMAX
    int*  bstarts = bcnt + NBMAX;                 // NBMAX
    int*  bcur    = bstarts + NBMAX;              // NBMAX
    int2* pairs   = (int2*)(bcur + NBMAX);        // n_edges int2 (8 MB)
    uint2* xb     = (uint2*)(pairs + n_edges);    // n_nodes*16 uint2 (12.8 MB)

    const size_t need = (size_t)3 * NBMAX * sizeof(int) +
                        (size_t)n_edges * sizeof(int2) +
                        (size_t)n_nodes * 16 * sizeof(uint2);

    if (nb > NBMAX || n_nodes > (1 << 24) || ws_size < need) {
        // fallback: R1 atomic path
        float* s = (float*)d_ws;
        hipMemsetAsync(s, 0, (size_t)n_nodes * D * sizeof(float), stream);
        gcn_scatter_kernel<<<(n_edges + 3) / 4, 256, 0, stream>>>(x, ew, src, tgt, s, n_edges);
        gcn_gemm_kernel<<<(n_nodes + 63) / 64, 256, 0, stream>>>(s, W, (float*)d_out, n_nodes);
        return;
    }

    hipMemsetAsync(bcnt, 0, (size_t)nb * sizeof(int), stream);

    const int ablocks = 256;
    const int epbA = (n_edges + ablocks - 1) / ablocks;
    convert_hist_kernel<<<ablocks, 256, 0, stream>>>(x, xb, n_nodes * 16,
                                                     tgt, bcnt, n_edges, nb, epbA);

    bucket_scan_kernel<<<1, 1024, 0, stream>>>(bcnt, bstarts, bcur, nb);

    const int cblocks = 256;
    const int epbC = (n_edges + cblocks - 1) / cblocks;
    bucket_scatter_kernel<<<cblocks, 256, 0, stream>>>(src, tgt, ew, bcur,
                                                       pairs, n_edges, nb, epbC);

    bucket_sort_reduce_gemm_kernel<<<nb, 512, 0, stream>>>(
        xb, W, bstarts, pairs, (float*)d_out, n_nodes, n_edges, nb);
}

// Round 11
// 119.111 us; speedup vs baseline: 1.1360x; 1.1360x over previous
//
#include <hip/hip_runtime.h>

// GCN block: delta = segment_sum( (x @ W^T)[source] * ew, target )
//          = segment_sum( x[source] * ew, target ) @ W^T   (linearity)
//
// R11: slack-slab bucket sort (no global prefix scan) + R9 gather/epilogue.
//  - Per-bucket fixed slab (CAPB): C reserves runs via global bcur atomics;
//    removes memset + hist-A + scan-B (5 dispatches -> 3).
//  - D holds its sort pairs in registers between hist and scatter passes
//    (saves an 8 MB global re-read per chunk).
//  - launch_bounds(512,8) pins VGPR<=64 -> full 32 waves/CU schedulable
//    (R10 showed VGPR 60 + wr4 epilogue cost occupancy; W back in LDS --
//    R10 also proved the 284K LDS conflicts are from the sort, not Wl).
// Tiered fallback: slack -> exact (R9-style) -> R1 atomics.

#define D     64     // D_IN == D_OUT == 64
#define BKT   64     // nodes per bucket
#define BSH   6      // log2(BKT)
#define NBMAX 2048   // max buckets (scan kernel / LDS hist limit)
#define CAP   1024   // edges per in-LDS sort chunk
#define CAPB  1024   // slack slots per bucket (mean 640, +15 sigma)

// ---------------- fallback: atomic edge scatter (R1) ----------------
__global__ __launch_bounds__(256) void gcn_scatter_kernel(
    const float* __restrict__ x, const float* __restrict__ ew,
    const int* __restrict__ src, const int* __restrict__ tgt,
    float* __restrict__ s, int n_edges)
{
    int lane = threadIdx.x & 63;
    int e = blockIdx.x * 4 + (threadIdx.x >> 6);
    if (e >= n_edges) return;
    int sn = src[e];
    int tn = tgt[e];
    float w = ew[e];
    float v = x[(size_t)sn * D + lane] * w;
    atomicAdd(&s[(size_t)tn * D + lane], v);
}

// ---------------- fallback: out = s @ W^T (R1) ----------------
__global__ __launch_bounds__(256) void gcn_gemm_kernel(
    const float* __restrict__ s, const float* __restrict__ W,
    float* __restrict__ out, int n_nodes)
{
    __shared__ float4 xs[64 * 17];
    const int tid  = threadIdx.x;
    const int lane = tid & 63;
    const int wid  = __builtin_amdgcn_readfirstlane(tid >> 6);
    const int row0 = blockIdx.x * 64;

    const float4* s4 = reinterpret_cast<const float4*>(s);
#pragma unroll
    for (int k = 0; k < 4; ++k) {
        int f  = tid + k * 256;
        int r  = f >> 4;
        int c4 = f & 15;
        float4 v = make_float4(0.f, 0.f, 0.f, 0.f);
        if (row0 + r < n_nodes)
            v = s4[(size_t)(row0 + r) * 16 + c4];
        xs[r * 17 + c4] = v;
    }
    __syncthreads();

    float acc[16];
#pragma unroll
    for (int j = 0; j < 16; ++j) acc[j] = 0.f;

    const int o0 = wid * 16;
    const float4* W4 = reinterpret_cast<const float4*>(W);
#pragma unroll
    for (int d4 = 0; d4 < 16; ++d4) {
        float4 xv = xs[lane * 17 + d4];
#pragma unroll
        for (int j = 0; j < 16; ++j) {
            float4 wv = W4[(size_t)(o0 + j) * 16 + d4];
            acc[j] += xv.x * wv.x + xv.y * wv.y + xv.z * wv.z + xv.w * wv.w;
        }
    }

    const int row = row0 + lane;
    if (row < n_nodes) {
        float4* out4 = reinterpret_cast<float4*>(out);
#pragma unroll
        for (int j4 = 0; j4 < 4; ++j4) {
            float4 v = make_float4(acc[j4 * 4 + 0], acc[j4 * 4 + 1],
                                   acc[j4 * 4 + 2], acc[j4 * 4 + 3]);
            out4[(size_t)row * 16 + wid * 4 + j4] = v;
        }
    }
}

__device__ __forceinline__ unsigned f2bf(float f) {
    unsigned u = __float_as_uint(f);
    return (u + 0x7FFFu + ((u >> 16) & 1u)) >> 16;   // RNE; inputs finite
}

// ---------------- A2 (slack): convert x->bf16 + init bbeg/bcur ------------
__global__ __launch_bounds__(256) void convert_init_kernel(
    const float* __restrict__ x, uint2* __restrict__ xb, int n4,
    int* __restrict__ bbeg, int* __restrict__ bcur, int nb)
{
    const int g = blockIdx.x * 256 + threadIdx.x;
    if (g < nb) { bbeg[g] = g * CAPB; bcur[g] = g * CAPB; }
    const float4* x4 = reinterpret_cast<const float4*>(x);
    for (int i = g; i < n4; i += gridDim.x * 256) {
        float4 v = x4[i];
        uint2 o;
        o.x = f2bf(v.x) | (f2bf(v.y) << 16);
        o.y = f2bf(v.z) | (f2bf(v.w) << 16);
        xb[i] = o;
    }
}

// ---------------- A (exact): convert + bucket histogram ----------------
__global__ __launch_bounds__(256) void convert_hist_kernel(
    const float* __restrict__ x, uint2* __restrict__ xb, int n4,
    const int* __restrict__ tgt, int* __restrict__ bcnt,
    int n_edges, int nb, int epb)
{
    __shared__ int h[NBMAX];
    const int tid = threadIdx.x;
    for (int i = tid; i < nb; i += 256) h[i] = 0;

    const float4* x4 = reinterpret_cast<const float4*>(x);
    for (int i = blockIdx.x * 256 + tid; i < n4; i += gridDim.x * 256) {
        float4 v = x4[i];
        uint2 o;
        o.x = f2bf(v.x) | (f2bf(v.y) << 16);
        o.y = f2bf(v.z) | (f2bf(v.w) << 16);
        xb[i] = o;
    }
    __syncthreads();

    const int e0 = blockIdx.x * epb;
    const int e1 = min(e0 + epb, n_edges);
    for (int e = e0 + tid; e < e1; e += 256)
        atomicAdd(&h[tgt[e] >> BSH], 1);
    __syncthreads();
    for (int b = tid; b < nb; b += 256) {
        int c = h[b];
        if (c) atomicAdd(&bcnt[b], c);
    }
}

// ---------------- B (exact): exclusive scan of bucket counts ----------
__global__ __launch_bounds__(1024) void bucket_scan_kernel(
    const int* __restrict__ bcnt, int* __restrict__ bstarts,
    int* __restrict__ bcur, int nb, int n_edges)
{
    __shared__ int lds[1024];
    const int tid = threadIdx.x;
    const int i0 = 2 * tid, i1 = 2 * tid + 1;
    int v0 = (i0 < nb) ? bcnt[i0] : 0;
    int v1 = (i1 < nb) ? bcnt[i1] : 0;
    int tsum = v0 + v1;
    lds[tid] = tsum;
    __syncthreads();
    for (int off = 1; off < 1024; off <<= 1) {
        int a = (tid >= off) ? lds[tid - off] : 0;
        __syncthreads();
        lds[tid] += a;
        __syncthreads();
    }
    int pre = lds[tid] - tsum;     // exclusive
    if (i0 < nb) { bstarts[i0] = pre;      bcur[i0] = pre; }
    if (i1 < nb) { bstarts[i1] = pre + v0; bcur[i1] = pre + v0; }
    if (tid == 0) bstarts[nb] = n_edges;   // sentinel so bend = bstarts+1
}

// ---------------- C: scatter edges into bucket runs (both paths) ----------
__global__ __launch_bounds__(256) void bucket_scatter_kernel(
    const int* __restrict__ src, const int* __restrict__ tgt,
    const float* __restrict__ ew, int* __restrict__ bcur,
    int2* __restrict__ pairs, int n_edges, int nb, int epb)
{
    __shared__ int h[NBMAX];        // counts, then rank counters
    __shared__ int base[NBMAX];
    const int tid = threadIdx.x;
    for (int i = tid; i < nb; i += 256) h[i] = 0;
    __syncthreads();
    const int e0 = blockIdx.x * epb;
    const int e1 = min(e0 + epb, n_edges);

    for (int e = e0 + tid; e < e1; e += 256)
        atomicAdd(&h[tgt[e] >> BSH], 1);
    __syncthreads();

    for (int b = tid; b < nb; b += 256) {
        int c = h[b];
        base[b] = c ? atomicAdd(&bcur[b], c) : 0;
        h[b] = 0;                   // reuse as rank counter
    }
    __syncthreads();

    for (int e = e0 + tid; e < e1; e += 256) {
        int t = tgt[e];
        int b = t >> BSH;
        int r = atomicAdd(&h[b], 1);
        pairs[base[b] + r] =
            make_int2(((t & (BKT - 1)) << 24) | src[e], __float_as_int(ew[e]));
    }
}

// ---------------- D: per-bucket LDS sort + bf16 quad-gather + GEMM --------
// One block per bucket (64 nodes), 8 waves, VGPR pinned <=64 by (512,8).
// Sort pairs held in registers between hist and scatter passes.
// Quarter q=lane>>4 handles edge e+q; dwordx2 fetches 4 bf16 feats.
// Epilogue: W in LDS (pad 66, float2, 2-way=free), accRow broadcast.
__global__ __launch_bounds__(512, 8) void bucket_sort_reduce_gemm_kernel(
    const uint2* __restrict__ xb, const float* __restrict__ W,
    const int* __restrict__ bbeg, const int* __restrict__ bend,
    const int2* __restrict__ pairs,
    float* __restrict__ out, int n_nodes, int nb)
{
    __shared__ float Wl[64 * 66];       // 16.9 KB; W[o][d] at Wl[o*66+d]
    __shared__ int2  ep[CAP];           // 8 KB, node-sorted chunk
    __shared__ int   segIncl[BKT];      // inclusive per-node counts
    __shared__ int   rankc[BKT];        // scatter cursors
    __shared__ float accRow[8][64];     // per-wave row buffer

    const int tid  = threadIdx.x;
    const int lane = tid & 63;
    const int wv   = tid >> 6;          // 0..7
    const int q4   = lane >> 4;         // quarter 0..3
    const int m    = lane & 15;         // feature-quad index

    for (int i = tid; i < 64 * 64; i += 512)
        Wl[(i >> 6) * 66 + (i & 63)] = W[i];

    const int b   = blockIdx.x;
    const int beg = bbeg[b];
    const int end = bend[b];

    float4 acc[8];
#pragma unroll
    for (int s = 0; s < 8; ++s) acc[s] = make_float4(0.f, 0.f, 0.f, 0.f);

    for (int cbeg = beg; cbeg < end; cbeg += CAP) {
        const int ccnt = min(CAP, end - cbeg);

        // -- load this chunk's pairs into registers (2 per thread) --
        int2 pr0 = make_int2(0, 0), pr1 = make_int2(0, 0);
        if (tid < ccnt)       pr0 = pairs[cbeg + tid];
        if (tid + 512 < ccnt) pr1 = pairs[cbeg + tid + 512];

        if (tid < BKT) segIncl[tid] = 0;
        __syncthreads();

        // -- pass 1: histogram tloc (from regs) --
        if (tid < ccnt)       atomicAdd(&segIncl[((unsigned)pr0.x) >> 24], 1);
        if (tid + 512 < ccnt) atomicAdd(&segIncl[((unsigned)pr1.x) >> 24], 1);
        __syncthreads();

        // -- 64-bin scan by wave 0 (shfl) --
        if (wv == 0) {
            int c0 = segIncl[lane];
            int v = c0;
#pragma unroll
            for (int off = 1; off < 64; off <<= 1) {
                int n = __shfl_up(v, off);
                if (lane >= off) v += n;
            }
            segIncl[lane] = v;          // inclusive
            rankc[lane]   = v - c0;     // exclusive start
        }
        __syncthreads();

        // -- pass 2: scatter into node-sorted LDS (from regs) --
        if (tid < ccnt) {
            int pos = atomicAdd(&rankc[((unsigned)pr0.x) >> 24], 1);
            ep[pos] = pr0;
        }
        if (tid + 512 < ccnt) {
            int pos = atomicAdd(&rankc[((unsigned)pr1.x) >> 24], 1);
            ep[pos] = pr1;
        }
        __syncthreads();

        // -- bf16 quad-gather segreduce: wave wv owns tl = s*8+wv --
#pragma unroll
        for (int s = 0; s < 8; ++s) {
            const int tl = s * 8 + wv;
            const int s0 = __builtin_amdgcn_readfirstlane(tl ? segIncl[tl - 1] : 0);
            const int s1 = __builtin_amdgcn_readfirstlane(segIncl[tl]);
            float4 a = acc[s];
            for (int e = s0; e < s1; e += 8) {
                const int ea = e + q4;
                const int eb = e + 4 + q4;
                int2 p0 = ep[min(ea, s1 - 1)];
                int2 p1 = ep[min(eb, s1 - 1)];
                float w0 = (ea < s1) ? __int_as_float(p0.y) : 0.f;
                float w1 = (eb < s1) ? __int_as_float(p1.y) : 0.f;
                uint2 r0 = xb[(size_t)(p0.x & 0xFFFFFF) * 16 + m];   // 4 bf16
                uint2 r1 = xb[(size_t)(p1.x & 0xFFFFFF) * 16 + m];
                a.x += w0 * __uint_as_float(r0.x << 16);
                a.y += w0 * __uint_as_float(r0.x & 0xFFFF0000u);
                a.z += w0 * __uint_as_float(r0.y << 16);
                a.w += w0 * __uint_as_float(r0.y & 0xFFFF0000u);
                a.x += w1 * __uint_as_float(r1.x << 16);
                a.y += w1 * __uint_as_float(r1.x & 0xFFFF0000u);
                a.z += w1 * __uint_as_float(r1.y << 16);
                a.w += w1 * __uint_as_float(r1.y & 0xFFFF0000u);
            }
            acc[s] = a;
        }
        __syncthreads();   // protect ep/segIncl before next chunk
    }

    // -- epilogue: merge quarters, out[node][o] = sum_d row[d]*W[o][d] --
    const int node0 = b * BKT;
#pragma unroll
    for (int s = 0; s < 8; ++s) {
        const int node = node0 + s * 8 + wv;
        if (node < n_nodes) {
            float4 a = acc[s];
            a.x += __shfl_xor(a.x, 16); a.y += __shfl_xor(a.y, 16);
            a.z += __shfl_xor(a.z, 16); a.w += __shfl_xor(a.w, 16);
            a.x += __shfl_xor(a.x, 32); a.y += __shfl_xor(a.y, 32);
            a.z += __shfl_xor(a.z, 32); a.w += __shfl_xor(a.w, 32);
            if (lane < 16)
                *reinterpret_cast<float4*>(&accRow[wv][m * 4]) = a;
            asm volatile("s_waitcnt lgkmcnt(0)" ::: "memory");

            float o = 0.f;
            const float2* a2 = reinterpret_cast<const float2*>(&accRow[wv][0]);
            const float2* w2 = reinterpret_cast<const float2*>(&Wl[lane * 66]);
#pragma unroll
            for (int d2 = 0; d2 < 32; ++d2) {
                float2 aq = a2[d2];    // broadcast
                float2 wq = w2[d2];
                o += aq.x * wq.x + aq.y * wq.y;
            }
            out[(size_t)node * D + lane] = o;
            asm volatile("s_waitcnt lgkmcnt(0)" ::: "memory"); // drain before overwrite
        }
    }
}

extern "C" void kernel_launch(void* const* d_in, const int* in_sizes, int n_in,
                              void* d_out, int out_size, void* d_ws, size_t ws_size,
                              hipStream_t stream)
{
    const float* x   = (const float*)d_in[0];
    const float* W   = (const float*)d_in[1];
    const float* ew  = (const float*)d_in[2];
    const int*   src = (const int*)d_in[3];
    const int*   tgt = (const int*)d_in[4];

    const int n_nodes = in_sizes[0] / D;
    const int n_edges = in_sizes[2];
    const int nb = (n_nodes + BKT - 1) / BKT;
    const int cblocks = 256;
    const int epbC = (n_edges + cblocks - 1) / cblocks;

    // ---- slack layout: [bcur nb][bbeg nb][pairs nb*CAPB][xb] ----
    {
        int*   bcur  = (int*)d_ws;
        int*   bbeg  = bcur + nb;
        size_t ints  = 2 * (size_t)nb;
        ints = (ints + 1) & ~(size_t)1;                 // 8B align
        int2*  pairs = (int2*)((int*)d_ws + ints);
        uint2* xb    = (uint2*)(pairs + (size_t)nb * CAPB);
        const size_t need = ints * 4 + (size_t)nb * CAPB * 8 +
                            (size_t)n_nodes * 128;

        if (nb <= NBMAX && n_nodes <= (1 << 24) && ws_size >= need) {
            convert_init_kernel<<<256, 256, 0, stream>>>(
                x, xb, n_nodes * 16, bbeg, bcur, nb);
            bucket_scatter_kernel<<<cblocks, 256, 0, stream>>>(
                src, tgt, ew, bcur, pairs, n_edges, nb, epbC);
            bucket_sort_reduce_gemm_kernel<<<nb, 512, 0, stream>>>(
                xb, W, bbeg, bcur, pairs, (float*)d_out, n_nodes, nb);
            return;
        }
    }

    // ---- exact layout: [bcnt NBMAX][bstarts NBMAX+1][bcur NBMAX][pairs][xb]
    {
        int*   bcnt    = (int*)d_ws;
        int*   bstarts = bcnt + NBMAX;
        int*   bcur    = bstarts + NBMAX + 1;
        size_t ints    = 3 * (size_t)NBMAX + 1;
        ints = (ints + 1) & ~(size_t)1;
        int2*  pairs   = (int2*)((int*)d_ws + ints);
        uint2* xb      = (uint2*)(pairs + n_edges);
        const size_t need = ints * 4 + (size_t)n_edges * 8 +
                            (size_t)n_nodes * 128;

        if (nb <= NBMAX && n_nodes <= (1 << 24) && ws_size >= need) {
            hipMemsetAsync(bcnt, 0, (size_t)nb * sizeof(int), stream);
            const int ablocks = 256;
            const int epbA = (n_edges + ablocks - 1) / ablocks;
            convert_hist_kernel<<<ablocks, 256, 0, stream>>>(
                x, xb, n_nodes * 16, tgt, bcnt, n_edges, nb, epbA);
            bucket_scan_kernel<<<1, 1024, 0, stream>>>(bcnt, bstarts, bcur,
                                                       nb, n_edges);
            bucket_scatter_kernel<<<cblocks, 256, 0, stream>>>(
                src, tgt, ew, bcur, pairs, n_edges, nb, epbC);
            bucket_sort_reduce_gemm_kernel<<<nb, 512, 0, stream>>>(
                xb, W, bstarts, bstarts + 1, pairs, (float*)d_out, n_nodes, nb);
            return;
        }
    }

    // ---- fallback: R1 atomic path ----
    float* s = (float*)d_ws;
    hipMemsetAsync(s, 0, (size_t)n_nodes * D * sizeof(float), stream);
    gcn_scatter_kernel<<<(n_edges + 3) / 4, 256, 0, stream>>>(x, ew, src, tgt, s, n_edges);
    gcn_gemm_kernel<<<(n_nodes + 63) / 64, 256, 0, stream>>>(s, W, (float*)d_out, n_nodes);
}

// Round 12
// 112.444 us; speedup vs baseline: 1.2034x; 1.0593x over previous
//
#include <hip/hip_runtime.h>

// GCN block: delta = segment_sum( (x @ W^T)[source] * ew, target )
//          = segment_sum( x[source] * ew, target ) @ W^T   (linearity)
//
// R12: R11 pipeline; D's gather loop restructured to 4-way SEGMENT
// INTERLEAVE per wave (2 unrolled groups of 4 segments, static accs):
// 16 rows in flight per wave (4 quad-gather loads) and ~2x fewer
// vmcnt stall points. R9-R11 proved bytes/occupancy don't move D
// (77-90us across 5 variants) -> attack the per-wave latency chain.

#define D     64     // D_IN == D_OUT == 64
#define BKT   64     // nodes per bucket
#define BSH   6      // log2(BKT)
#define NBMAX 2048   // max buckets (scan kernel / LDS hist limit)
#define CAP   1024   // edges per in-LDS sort chunk
#define CAPB  1024   // slack slots per bucket (mean 640, +15 sigma)

// ---------------- fallback: atomic edge scatter (R1) ----------------
__global__ __launch_bounds__(256) void gcn_scatter_kernel(
    const float* __restrict__ x, const float* __restrict__ ew,
    const int* __restrict__ src, const int* __restrict__ tgt,
    float* __restrict__ s, int n_edges)
{
    int lane = threadIdx.x & 63;
    int e = blockIdx.x * 4 + (threadIdx.x >> 6);
    if (e >= n_edges) return;
    int sn = src[e];
    int tn = tgt[e];
    float w = ew[e];
    float v = x[(size_t)sn * D + lane] * w;
    atomicAdd(&s[(size_t)tn * D + lane], v);
}

// ---------------- fallback: out = s @ W^T (R1) ----------------
__global__ __launch_bounds__(256) void gcn_gemm_kernel(
    const float* __restrict__ s, const float* __restrict__ W,
    float* __restrict__ out, int n_nodes)
{
    __shared__ float4 xs[64 * 17];
    const int tid  = threadIdx.x;
    const int lane = tid & 63;
    const int wid  = __builtin_amdgcn_readfirstlane(tid >> 6);
    const int row0 = blockIdx.x * 64;

    const float4* s4 = reinterpret_cast<const float4*>(s);
#pragma unroll
    for (int k = 0; k < 4; ++k) {
        int f  = tid + k * 256;
        int r  = f >> 4;
        int c4 = f & 15;
        float4 v = make_float4(0.f, 0.f, 0.f, 0.f);
        if (row0 + r < n_nodes)
            v = s4[(size_t)(row0 + r) * 16 + c4];
        xs[r * 17 + c4] = v;
    }
    __syncthreads();

    float acc[16];
#pragma unroll
    for (int j = 0; j < 16; ++j) acc[j] = 0.f;

    const int o0 = wid * 16;
    const float4* W4 = reinterpret_cast<const float4*>(W);
#pragma unroll
    for (int d4 = 0; d4 < 16; ++d4) {
        float4 xv = xs[lane * 17 + d4];
#pragma unroll
        for (int j = 0; j < 16; ++j) {
            float4 wv = W4[(size_t)(o0 + j) * 16 + d4];
            acc[j] += xv.x * wv.x + xv.y * wv.y + xv.z * wv.z + xv.w * wv.w;
        }
    }

    const int row = row0 + lane;
    if (row < n_nodes) {
        float4* out4 = reinterpret_cast<float4*>(out);
#pragma unroll
        for (int j4 = 0; j4 < 4; ++j4) {
            float4 v = make_float4(acc[j4 * 4 + 0], acc[j4 * 4 + 1],
                                   acc[j4 * 4 + 2], acc[j4 * 4 + 3]);
            out4[(size_t)row * 16 + wid * 4 + j4] = v;
        }
    }
}

__device__ __forceinline__ unsigned f2bf(float f) {
    unsigned u = __float_as_uint(f);
    return (u + 0x7FFFu + ((u >> 16) & 1u)) >> 16;   // RNE; inputs finite
}

// ---------------- A2 (slack): convert x->bf16 + init bbeg/bcur ------------
__global__ __launch_bounds__(256) void convert_init_kernel(
    const float* __restrict__ x, uint2* __restrict__ xb, int n4,
    int* __restrict__ bbeg, int* __restrict__ bcur, int nb)
{
    const int g = blockIdx.x * 256 + threadIdx.x;
    if (g < nb) { bbeg[g] = g * CAPB; bcur[g] = g * CAPB; }
    const float4* x4 = reinterpret_cast<const float4*>(x);
    for (int i = g; i < n4; i += gridDim.x * 256) {
        float4 v = x4[i];
        uint2 o;
        o.x = f2bf(v.x) | (f2bf(v.y) << 16);
        o.y = f2bf(v.z) | (f2bf(v.w) << 16);
        xb[i] = o;
    }
}

// ---------------- A (exact): convert + bucket histogram ----------------
__global__ __launch_bounds__(256) void convert_hist_kernel(
    const float* __restrict__ x, uint2* __restrict__ xb, int n4,
    const int* __restrict__ tgt, int* __restrict__ bcnt,
    int n_edges, int nb, int epb)
{
    __shared__ int h[NBMAX];
    const int tid = threadIdx.x;
    for (int i = tid; i < nb; i += 256) h[i] = 0;

    const float4* x4 = reinterpret_cast<const float4*>(x);
    for (int i = blockIdx.x * 256 + tid; i < n4; i += gridDim.x * 256) {
        float4 v = x4[i];
        uint2 o;
        o.x = f2bf(v.x) | (f2bf(v.y) << 16);
        o.y = f2bf(v.z) | (f2bf(v.w) << 16);
        xb[i] = o;
    }
    __syncthreads();

    const int e0 = blockIdx.x * epb;
    const int e1 = min(e0 + epb, n_edges);
    for (int e = e0 + tid; e < e1; e += 256)
        atomicAdd(&h[tgt[e] >> BSH], 1);
    __syncthreads();
    for (int b = tid; b < nb; b += 256) {
        int c = h[b];
        if (c) atomicAdd(&bcnt[b], c);
    }
}

// ---------------- B (exact): exclusive scan of bucket counts ----------
__global__ __launch_bounds__(1024) void bucket_scan_kernel(
    const int* __restrict__ bcnt, int* __restrict__ bstarts,
    int* __restrict__ bcur, int nb, int n_edges)
{
    __shared__ int lds[1024];
    const int tid = threadIdx.x;
    const int i0 = 2 * tid, i1 = 2 * tid + 1;
    int v0 = (i0 < nb) ? bcnt[i0] : 0;
    int v1 = (i1 < nb) ? bcnt[i1] : 0;
    int tsum = v0 + v1;
    lds[tid] = tsum;
    __syncthreads();
    for (int off = 1; off < 1024; off <<= 1) {
        int a = (tid >= off) ? lds[tid - off] : 0;
        __syncthreads();
        lds[tid] += a;
        __syncthreads();
    }
    int pre = lds[tid] - tsum;     // exclusive
    if (i0 < nb) { bstarts[i0] = pre;      bcur[i0] = pre; }
    if (i1 < nb) { bstarts[i1] = pre + v0; bcur[i1] = pre + v0; }
    if (tid == 0) bstarts[nb] = n_edges;   // sentinel so bend = bstarts+1
}

// ---------------- C: scatter edges into bucket runs (both paths) ----------
__global__ __launch_bounds__(256) void bucket_scatter_kernel(
    const int* __restrict__ src, const int* __restrict__ tgt,
    const float* __restrict__ ew, int* __restrict__ bcur,
    int2* __restrict__ pairs, int n_edges, int nb, int epb)
{
    __shared__ int h[NBMAX];        // counts, then rank counters
    __shared__ int base[NBMAX];
    const int tid = threadIdx.x;
    for (int i = tid; i < nb; i += 256) h[i] = 0;
    __syncthreads();
    const int e0 = blockIdx.x * epb;
    const int e1 = min(e0 + epb, n_edges);

    for (int e = e0 + tid; e < e1; e += 256)
        atomicAdd(&h[tgt[e] >> BSH], 1);
    __syncthreads();

    for (int b = tid; b < nb; b += 256) {
        int c = h[b];
        base[b] = c ? atomicAdd(&bcur[b], c) : 0;
        h[b] = 0;                   // reuse as rank counter
    }
    __syncthreads();

    for (int e = e0 + tid; e < e1; e += 256) {
        int t = tgt[e];
        int b = t >> BSH;
        int r = atomicAdd(&h[b], 1);
        pairs[base[b] + r] =
            make_int2(((t & (BKT - 1)) << 24) | src[e], __float_as_int(ew[e]));
    }
}

// ---------------- D: per-bucket LDS sort + 4-way-interleaved gather + GEMM -
// One block per bucket (64 nodes), 8 waves. Wave wv owns nodes
// tl = s*8+wv, s = g*4+k. The 4 segments of a group advance together in
// one uniform while-loop: 4 quad-gather loads/iter = 16 rows in flight.
__global__ __launch_bounds__(512, 6) void bucket_sort_reduce_gemm_kernel(
    const uint2* __restrict__ xb, const float* __restrict__ W,
    const int* __restrict__ bbeg, const int* __restrict__ bend,
    const int2* __restrict__ pairs,
    float* __restrict__ out, int n_nodes, int nb)
{
    __shared__ float Wl[64 * 66];       // 16.9 KB; W[o][d] at Wl[o*66+d]
    __shared__ int2  ep[CAP];           // 8 KB, node-sorted chunk
    __shared__ int   segIncl[BKT];      // inclusive per-node counts
    __shared__ int   rankc[BKT];        // scatter cursors
    __shared__ float accRow[8][64];     // per-wave row buffer

    const int tid  = threadIdx.x;
    const int lane = tid & 63;
    const int wv   = tid >> 6;          // 0..7
    const int q4   = lane >> 4;         // quarter 0..3
    const int m    = lane & 15;         // feature-quad index

    for (int i = tid; i < 64 * 64; i += 512)
        Wl[(i >> 6) * 66 + (i & 63)] = W[i];

    const int b   = blockIdx.x;
    const int beg = bbeg[b];
    const int end = bend[b];

    float4 acc[8];
#pragma unroll
    for (int s = 0; s < 8; ++s) acc[s] = make_float4(0.f, 0.f, 0.f, 0.f);

    for (int cbeg = beg; cbeg < end; cbeg += CAP) {
        const int ccnt = min(CAP, end - cbeg);

        // -- load this chunk's pairs into registers (2 per thread) --
        int2 pr0 = make_int2(0, 0), pr1 = make_int2(0, 0);
        if (tid < ccnt)       pr0 = pairs[cbeg + tid];
        if (tid + 512 < ccnt) pr1 = pairs[cbeg + tid + 512];

        if (tid < BKT) segIncl[tid] = 0;
        __syncthreads();

        // -- pass 1: histogram tloc (from regs) --
        if (tid < ccnt)       atomicAdd(&segIncl[((unsigned)pr0.x) >> 24], 1);
        if (tid + 512 < ccnt) atomicAdd(&segIncl[((unsigned)pr1.x) >> 24], 1);
        __syncthreads();

        // -- 64-bin scan by wave 0 (shfl) --
        if (wv == 0) {
            int c0 = segIncl[lane];
            int v = c0;
#pragma unroll
            for (int off = 1; off < 64; off <<= 1) {
                int n = __shfl_up(v, off);
                if (lane >= off) v += n;
            }
            segIncl[lane] = v;          // inclusive
            rankc[lane]   = v - c0;     // exclusive start
        }
        __syncthreads();

        // -- pass 2: scatter into node-sorted LDS (from regs) --
        if (tid < ccnt) {
            int pos = atomicAdd(&rankc[((unsigned)pr0.x) >> 24], 1);
            ep[pos] = pr0;
        }
        if (tid + 512 < ccnt) {
            int pos = atomicAdd(&rankc[((unsigned)pr1.x) >> 24], 1);
            ep[pos] = pr1;
        }
        __syncthreads();

        // -- 4-way interleaved quad-gather: group g covers s = g*4+k --
#pragma unroll
        for (int g = 0; g < 2; ++g) {
            int e0, e1, e2, e3, x1_0, x1_1, x1_2, x1_3;
            {
                const int tl0 = (g * 4 + 0) * 8 + wv;
                const int tl1 = (g * 4 + 1) * 8 + wv;
                const int tl2 = (g * 4 + 2) * 8 + wv;
                const int tl3 = (g * 4 + 3) * 8 + wv;
                e0 = __builtin_amdgcn_readfirstlane(tl0 ? segIncl[tl0 - 1] : 0);
                e1 = __builtin_amdgcn_readfirstlane(segIncl[tl1 - 1]);
                e2 = __builtin_amdgcn_readfirstlane(segIncl[tl2 - 1]);
                e3 = __builtin_amdgcn_readfirstlane(segIncl[tl3 - 1]);
                x1_0 = __builtin_amdgcn_readfirstlane(segIncl[tl0]);
                x1_1 = __builtin_amdgcn_readfirstlane(segIncl[tl1]);
                x1_2 = __builtin_amdgcn_readfirstlane(segIncl[tl2]);
                x1_3 = __builtin_amdgcn_readfirstlane(segIncl[tl3]);
            }
            const int c1_0 = max(x1_0 - 1, 0);
            const int c1_1 = max(x1_1 - 1, 0);
            const int c1_2 = max(x1_2 - 1, 0);
            const int c1_3 = max(x1_3 - 1, 0);
            float4 a0 = acc[g * 4 + 0];
            float4 a1 = acc[g * 4 + 1];
            float4 a2 = acc[g * 4 + 2];
            float4 a3 = acc[g * 4 + 3];

            while ((e0 < x1_0) | (e1 < x1_1) | (e2 < x1_2) | (e3 < x1_3)) {
                const int ea0 = e0 + q4, ea1 = e1 + q4;
                const int ea2 = e2 + q4, ea3 = e3 + q4;
                int2 p0 = ep[min(ea0, c1_0)];
                int2 p1 = ep[min(ea1, c1_1)];
                int2 p2 = ep[min(ea2, c1_2)];
                int2 p3 = ep[min(ea3, c1_3)];
                // 4 independent quad-gathers -> 16 rows in flight
                uint2 r0 = xb[(size_t)(p0.x & 0xFFFFFF) * 16 + m];
                uint2 r1 = xb[(size_t)(p1.x & 0xFFFFFF) * 16 + m];
                uint2 r2 = xb[(size_t)(p2.x & 0xFFFFFF) * 16 + m];
                uint2 r3 = xb[(size_t)(p3.x & 0xFFFFFF) * 16 + m];
                float w0 = (ea0 < x1_0) ? __int_as_float(p0.y) : 0.f;
                float w1 = (ea1 < x1_1) ? __int_as_float(p1.y) : 0.f;
                float w2 = (ea2 < x1_2) ? __int_as_float(p2.y) : 0.f;
                float w3 = (ea3 < x1_3) ? __int_as_float(p3.y) : 0.f;
                a0.x += w0 * __uint_as_float(r0.x << 16);
                a0.y += w0 * __uint_as_float(r0.x & 0xFFFF0000u);
                a0.z += w0 * __uint_as_float(r0.y << 16);
                a0.w += w0 * __uint_as_float(r0.y & 0xFFFF0000u);
                a1.x += w1 * __uint_as_float(r1.x << 16);
                a1.y += w1 * __uint_as_float(r1.x & 0xFFFF0000u);
                a1.z += w1 * __uint_as_float(r1.y << 16);
                a1.w += w1 * __uint_as_float(r1.y & 0xFFFF0000u);
                a2.x += w2 * __uint_as_float(r2.x << 16);
                a2.y += w2 * __uint_as_float(r2.x & 0xFFFF0000u);
                a2.z += w2 * __uint_as_float(r2.y << 16);
                a2.w += w2 * __uint_as_float(r2.y & 0xFFFF0000u);
                a3.x += w3 * __uint_as_float(r3.x << 16);
                a3.y += w3 * __uint_as_float(r3.x & 0xFFFF0000u);
                a3.z += w3 * __uint_as_float(r3.y << 16);
                a3.w += w3 * __uint_as_float(r3.y & 0xFFFF0000u);
                e0 += 4; e1 += 4; e2 += 4; e3 += 4;
            }
            acc[g * 4 + 0] = a0;
            acc[g * 4 + 1] = a1;
            acc[g * 4 + 2] = a2;
            acc[g * 4 + 3] = a3;
        }
        __syncthreads();   // protect ep/segIncl before next chunk
    }

    // -- epilogue: merge quarters, out[node][o] = sum_d row[d]*W[o][d] --
    const int node0 = b * BKT;
#pragma unroll
    for (int s = 0; s < 8; ++s) {
        const int node = node0 + s * 8 + wv;
        if (node < n_nodes) {
            float4 a = acc[s];
            a.x += __shfl_xor(a.x, 16); a.y += __shfl_xor(a.y, 16);
            a.z += __shfl_xor(a.z, 16); a.w += __shfl_xor(a.w, 16);
            a.x += __shfl_xor(a.x, 32); a.y += __shfl_xor(a.y, 32);
            a.z += __shfl_xor(a.z, 32); a.w += __shfl_xor(a.w, 32);
            if (lane < 16)
                *reinterpret_cast<float4*>(&accRow[wv][m * 4]) = a;
            asm volatile("s_waitcnt lgkmcnt(0)" ::: "memory");

            float o = 0.f;
            const float2* a2p = reinterpret_cast<const float2*>(&accRow[wv][0]);
            const float2* w2p = reinterpret_cast<const float2*>(&Wl[lane * 66]);
#pragma unroll
            for (int d2 = 0; d2 < 32; ++d2) {
                float2 aq = a2p[d2];   // broadcast
                float2 wq = w2p[d2];
                o += aq.x * wq.x + aq.y * wq.y;
            }
            out[(size_t)node * D + lane] = o;
            asm volatile("s_waitcnt lgkmcnt(0)" ::: "memory"); // drain before overwrite
        }
    }
}

extern "C" void kernel_launch(void* const* d_in, const int* in_sizes, int n_in,
                              void* d_out, int out_size, void* d_ws, size_t ws_size,
                              hipStream_t stream)
{
    const float* x   = (const float*)d_in[0];
    const float* W   = (const float*)d_in[1];
    const float* ew  = (const float*)d_in[2];
    const int*   src = (const int*)d_in[3];
    const int*   tgt = (const int*)d_in[4];

    const int n_nodes = in_sizes[0] / D;
    const int n_edges = in_sizes[2];
    const int nb = (n_nodes + BKT - 1) / BKT;
    const int cblocks = 256;
    const int epbC = (n_edges + cblocks - 1) / cblocks;

    // ---- slack layout: [bcur nb][bbeg nb][pairs nb*CAPB][xb] ----
    {
        int*   bcur  = (int*)d_ws;
        int*   bbeg  = bcur + nb;
        size_t ints  = 2 * (size_t)nb;
        ints = (ints + 1) & ~(size_t)1;                 // 8B align
        int2*  pairs = (int2*)((int*)d_ws + ints);
        uint2* xb    = (uint2*)(pairs + (size_t)nb * CAPB);
        const size_t need = ints * 4 + (size_t)nb * CAPB * 8 +
                            (size_t)n_nodes * 128;

        if (nb <= NBMAX && n_nodes <= (1 << 24) && ws_size >= need) {
            convert_init_kernel<<<256, 256, 0, stream>>>(
                x, xb, n_nodes * 16, bbeg, bcur, nb);
            bucket_scatter_kernel<<<cblocks, 256, 0, stream>>>(
                src, tgt, ew, bcur, pairs, n_edges, nb, epbC);
            bucket_sort_reduce_gemm_kernel<<<nb, 512, 0, stream>>>(
                xb, W, bbeg, bcur, pairs, (float*)d_out, n_nodes, nb);
            return;
        }
    }

    // ---- exact layout: [bcnt NBMAX][bstarts NBMAX+1][bcur NBMAX][pairs][xb]
    {
        int*   bcnt    = (int*)d_ws;
        int*   bstarts = bcnt + NBMAX;
        int*   bcur    = bstarts + NBMAX + 1;
        size_t ints    = 3 * (size_t)NBMAX + 1;
        ints = (ints + 1) & ~(size_t)1;
        int2*  pairs   = (int2*)((int*)d_ws + ints);
        uint2* xb      = (uint2*)(pairs + n_edges);
        const size_t need = ints * 4 + (size_t)n_edges * 8 +
                            (size_t)n_nodes * 128;

        if (nb <= NBMAX && n_nodes <= (1 << 24) && ws_size >= need) {
            hipMemsetAsync(bcnt, 0, (size_t)nb * sizeof(int), stream);
            const int ablocks = 256;
            const int epbA = (n_edges + ablocks - 1) / ablocks;
            convert_hist_kernel<<<ablocks, 256, 0, stream>>>(
                x, xb, n_nodes * 16, tgt, bcnt, n_edges, nb, epbA);
            bucket_scan_kernel<<<1, 1024, 0, stream>>>(bcnt, bstarts, bcur,
                                                       nb, n_edges);
            bucket_scatter_kernel<<<cblocks, 256, 0, stream>>>(
                src, tgt, ew, bcur, pairs, n_edges, nb, epbC);
            bucket_sort_reduce_gemm_kernel<<<nb, 512, 0, stream>>>(
                xb, W, bstarts, bstarts + 1, pairs, (float*)d_out, n_nodes, nb);
            return;
        }
    }

    // ---- fallback: R1 atomic path ----
    float* s = (float*)d_ws;
    hipMemsetAsync(s, 0, (size_t)n_nodes * D * sizeof(float), stream);
    gcn_scatter_kernel<<<(n_edges + 3) / 4, 256, 0, stream>>>(x, ew, src, tgt, s, n_edges);
    gcn_gemm_kernel<<<(n_nodes + 63) / 64, 256, 0, stream>>>(s, W, (float*)d_out, n_nodes);
}